// Round 3
// baseline (551.665 us; speedup 1.0000x reference)
//
#include <hip/hip_runtime.h>
#include <stdint.h>

// ---------- types & helpers ----------
typedef short bf16x8 __attribute__((ext_vector_type(8)));
typedef float f32x4 __attribute__((ext_vector_type(4)));

__device__ __forceinline__ uint16_t f2b(float f) {
    uint32_t u = __builtin_bit_cast(uint32_t, f);
    return (uint16_t)((u + 0x7fffu + ((u >> 16) & 1u)) >> 16);
}

__device__ __forceinline__ void gll16(const void* g, void* l) {
    __builtin_amdgcn_global_load_lds(
        (const __attribute__((address_space(1))) uint32_t*)(uintptr_t)g,
        (__attribute__((address_space(3))) uint32_t*)(uint32_t)(uintptr_t)l,
        16, 0, 0);
}

// ---------- fp32 -> bf16 convert (x) ----------
__global__ __launch_bounds__(256) void cvt_f32_bf16(const float4* __restrict__ in,
                                                    uint2* __restrict__ out, int nvec) {
    int i = blockIdx.x * 256 + threadIdx.x;
    if (i >= nvec) return;
    float4 v = in[i];
    uint2 o;
    o.x = (uint32_t)f2b(v.x) | ((uint32_t)f2b(v.y) << 16);
    o.y = (uint32_t)f2b(v.z) | ((uint32_t)f2b(v.w) << 16);
    out[i] = o;
}

// ---------- weight transpose into PACKED layout ----------
// Packed Bt rows [4096][1024]: block g=row>>7: g<16 -> {QL 64 rows | QR 64 rows} for
// e in [g*64, g*64+64); g>=16 -> {K | V} for e in [(g-16)*64, ...).
struct Ptr4 { const float* p[4]; };

__global__ __launch_bounds__(256) void tr_w_packed(Ptr4 wp, uint16_t* __restrict__ out) {
    const int m = blockIdx.z;                  // 0=QL 1=QR 2=K 3=V
    const float* in = wp.p[m];
    __shared__ uint16_t tile[64][68];
    int t = threadIdx.x;
    int r0 = blockIdx.y * 64;                  // d-tile
    int c0 = blockIdx.x * 64;                  // e-tile
    for (int p = 0; p < 4; p++) {
        int row = p * 16 + (t >> 4);
        int c4 = (t & 15) * 4;
        float4 v = *(const float4*)&in[(size_t)(r0 + row) * 1024 + c0 + c4];
        tile[row][c4 + 0] = f2b(v.x);
        tile[row][c4 + 1] = f2b(v.y);
        tile[row][c4 + 2] = f2b(v.z);
        tile[row][c4 + 3] = f2b(v.w);
    }
    __syncthreads();
    // packed row base for this (matrix, e-tile)
    const int prow_base = (m >> 1) * 2048 + blockIdx.x * 128 + (m & 1) * 64;
    for (int p = 0; p < 4; p++) {
        int a = p * 16 + (t >> 4);             // local e index
        int b4 = (t & 15) * 4;
        uint32_t x0 = tile[b4 + 0][a], x1 = tile[b4 + 1][a];
        uint32_t x2 = tile[b4 + 2][a], x3 = tile[b4 + 3][a];
        uint2 pk;
        pk.x = x0 | (x1 << 16);
        pk.y = x2 | (x3 << 16);
        *(uint2*)&out[(size_t)(prow_base + a) * 1024 + r0 + b4] = pk;
    }
}

// ---------- packed projection GEMM ----------
// A[16384][1024] bf16, B = packed Wt [4096][1024].
// grid (32, 128). blockIdx.x<16: gate epilogue -> Q[m][e] bf16.
// blockIdx.x>=16: transpose epilogue -> KT/VT [b][e][tok] bf16.
union SmemP {
    struct { uint16_t lA[4096]; uint16_t lB[4096]; } s;   // 16 KB staging
    float ep[2][4096];                                     // 32 KB gate exchange
    uint16_t tr[4][64][68];                                // 34816 B transpose scratch
};

__global__ __launch_bounds__(256) void proj_packed(const uint16_t* __restrict__ A,
                                                   const uint16_t* __restrict__ B,
                                                   uint16_t* __restrict__ Q,
                                                   uint16_t* __restrict__ KT,
                                                   uint16_t* __restrict__ VT) {
    __shared__ SmemP u;
    const int t = threadIdx.x;
    const int wave = t >> 6;
    const int lane = t & 63;
    const int m0 = blockIdx.y * 128;
    const int n0 = blockIdx.x * 128;
    const int wm = (wave >> 1) * 64;
    const int wn = (wave & 1) * 64;

    // staging: lane t covers LDS slot [row=t>>2][chunk=t&3]; fetches global chunk
    // (t&3) ^ ((row>>1)&3)  (xor-swizzle; same 64B global segment per 4 lanes)
    const int gcol = (((t & 3) ^ ((t >> 3) & 3)) * 8);
    const uint16_t* gA0 = A + (size_t)(m0 + (t >> 2)) * 1024 + gcol;
    const uint16_t* gB0 = B + (size_t)(n0 + (t >> 2)) * 1024 + gcol;
    uint16_t* lA0 = u.s.lA + wave * 512;
    uint16_t* lA1 = u.s.lA + 2048 + wave * 512;
    uint16_t* lB0 = u.s.lB + wave * 512;
    uint16_t* lB1 = u.s.lB + 2048 + wave * 512;

    f32x4 acc[4][4] = {};

    const int arow = wm + (lane & 15);
    const int brow = wn + (lane & 15);
    // fragment k-chunk lane>>4 lives at LDS chunk (lane>>4) ^ ((row>>1)&3)
    const int swz = (((lane >> 4) ^ (((lane & 15) >> 1) & 3)) * 8);

    for (int k0 = 0; k0 < 1024; k0 += 32) {
        __syncthreads();
        gll16(gA0 + k0, lA0);
        gll16(gA0 + (size_t)64 * 1024 + k0, lA1);
        gll16(gB0 + k0, lB0);
        gll16(gB0 + (size_t)64 * 1024 + k0, lB1);
        __syncthreads();

        bf16x8 af[4], bfr[4];
#pragma unroll
        for (int i = 0; i < 4; i++)
            af[i] = *(const bf16x8*)&u.s.lA[(arow + i * 16) * 32 + swz];
#pragma unroll
        for (int i = 0; i < 4; i++)
            bfr[i] = *(const bf16x8*)&u.s.lB[(brow + i * 16) * 32 + swz];
#pragma unroll
        for (int i = 0; i < 4; i++)
#pragma unroll
            for (int j = 0; j < 4; j++)
                acc[i][j] = __builtin_amdgcn_mfma_f32_16x16x32_bf16(af[i], bfr[j],
                                                                    acc[i][j], 0, 0, 0);
    }

    __syncthreads();   // all waves done reading staging LDS before epilogue reuse

    const int rl = (lane >> 4) * 4;
    const int cl = lane & 15;

    if (blockIdx.x < 16) {
        // ---- gate epilogue: pair (wave, wave^1) share m-rows; wn=0 holds QL, wn=1 QR
        if (wave & 1) {
            float* ep = u.ep[wave >> 1];
#pragma unroll
            for (int i = 0; i < 4; i++)
#pragma unroll
                for (int j = 0; j < 4; j++)
#pragma unroll
                    for (int r = 0; r < 4; r++)
                        ep[(i * 16 + rl + r) * 64 + j * 16 + cl] = acc[i][j][r];
        }
        __syncthreads();
        if (!(wave & 1)) {
            const float* ep = u.ep[wave >> 1];
            const int e0 = blockIdx.x * 64;
#pragma unroll
            for (int i = 0; i < 4; i++)
#pragma unroll
                for (int j = 0; j < 4; j++)
#pragma unroll
                    for (int r = 0; r < 4; r++) {
                        float g = acc[i][j][r] * ep[(i * 16 + rl + r) * 64 + j * 16 + cl];
                        Q[(size_t)(m0 + wm + i * 16 + rl + r) * 1024 + e0 + j * 16 + cl] = f2b(g);
                    }
        }
    } else {
        // ---- K/V transpose epilogue: wn=0 wave holds K cols, wn=1 V cols
        const int batch = m0 >> 12;
        const int tok0 = (m0 & 4095) + wm;
        const int e0 = (blockIdx.x - 16) * 64;
        uint16_t* O = ((wave & 1) ? VT : KT) + (size_t)batch * 4194304;
#pragma unroll
        for (int i = 0; i < 4; i++)
#pragma unroll
            for (int j = 0; j < 4; j++) {
                int col = j * 16 + cl;
                int row0 = i * 16 + rl;
                uint2 pk;
                pk.x = (uint32_t)f2b(acc[i][j][0]) | ((uint32_t)f2b(acc[i][j][1]) << 16);
                pk.y = (uint32_t)f2b(acc[i][j][2]) | ((uint32_t)f2b(acc[i][j][3]) << 16);
                *(uint2*)&u.tr[wave][col][row0] = pk;
            }
        __builtin_amdgcn_s_waitcnt(0);   // drain LDS writes before cross-lane reads
#pragma unroll
        for (int dd = 0; dd < 16; dd++) {
            int f = dd * 4 + (lane >> 4);
            int t4 = cl * 4;
            uint2 v = *(const uint2*)&u.tr[wave][f][t4];
            *(uint2*)&O[(size_t)(e0 + f) * 4096 + tok0 + t4] = v;
        }
    }
}

// ---------- split-K kv GEMM: P[z] = VT-slice @ KT-slice^T, fp32 partials ----------
__global__ __launch_bounds__(256) void gemm_kv_splitk(const uint16_t* __restrict__ VT,
                                                      const uint16_t* __restrict__ KT,
                                                      float* __restrict__ P) {
    const int z = blockIdx.z;
    const int batch = z >> 2, ks = z & 3;
    const uint16_t* Ab = VT + (size_t)batch * 4194304 + ks * 1024;
    const uint16_t* Bb = KT + (size_t)batch * 4194304 + ks * 1024;

    __shared__ uint16_t lA[4096];
    __shared__ uint16_t lB[4096];

    const int t = threadIdx.x;
    const int wave = t >> 6;
    const int lane = t & 63;
    const int m0 = blockIdx.y * 128;
    const int n0 = blockIdx.x * 128;
    const int wm = (wave >> 1) * 64;
    const int wn = (wave & 1) * 64;

    const int gcol = (((t & 3) ^ ((t >> 3) & 3)) * 8);
    const uint16_t* gA0 = Ab + (size_t)(m0 + (t >> 2)) * 4096 + gcol;
    const uint16_t* gB0 = Bb + (size_t)(n0 + (t >> 2)) * 4096 + gcol;
    uint16_t* lA0 = lA + wave * 512;
    uint16_t* lA1 = lA + 2048 + wave * 512;
    uint16_t* lB0 = lB + wave * 512;
    uint16_t* lB1 = lB + 2048 + wave * 512;

    f32x4 acc[4][4] = {};

    const int arow = wm + (lane & 15);
    const int brow = wn + (lane & 15);
    const int swz = (((lane >> 4) ^ (((lane & 15) >> 1) & 3)) * 8);

    for (int k0 = 0; k0 < 1024; k0 += 32) {
        __syncthreads();
        gll16(gA0 + k0, lA0);
        gll16(gA0 + (size_t)64 * 4096 + k0, lA1);
        gll16(gB0 + k0, lB0);
        gll16(gB0 + (size_t)64 * 4096 + k0, lB1);
        __syncthreads();

        bf16x8 af[4], bfr[4];
#pragma unroll
        for (int i = 0; i < 4; i++)
            af[i] = *(const bf16x8*)&lA[(arow + i * 16) * 32 + swz];
#pragma unroll
        for (int i = 0; i < 4; i++)
            bfr[i] = *(const bf16x8*)&lB[(brow + i * 16) * 32 + swz];
#pragma unroll
        for (int i = 0; i < 4; i++)
#pragma unroll
            for (int j = 0; j < 4; j++)
                acc[i][j] = __builtin_amdgcn_mfma_f32_16x16x32_bf16(af[i], bfr[j],
                                                                    acc[i][j], 0, 0, 0);
    }

    float* Pb = P + (size_t)z * 1048576;
    const int crow = m0 + wm + (lane >> 4) * 4;
    const int ccol = n0 + wn + (lane & 15);
#pragma unroll
    for (int i = 0; i < 4; i++)
#pragma unroll
        for (int j = 0; j < 4; j++)
#pragma unroll
            for (int r = 0; r < 4; r++)
                Pb[(size_t)(crow + i * 16 + r) * 1024 + ccol + j * 16] = acc[i][j][r];
}

// ---------- reduce 4 fp32 partials -> bf16 kvT ----------
__global__ __launch_bounds__(256) void reduce_kv(const float4* __restrict__ P,
                                                 uint2* __restrict__ kvT) {
    int i = blockIdx.x * 256 + threadIdx.x;
    int b = i >> 18;
    int r = i & 262143;
    const float4* base = P + (size_t)b * 1048576 + r;
    float4 s0 = base[0];
    float4 s1 = base[262144];
    float4 s2 = base[524288];
    float4 s3 = base[786432];
    float x = s0.x + s1.x + s2.x + s3.x;
    float y = s0.y + s1.y + s2.y + s3.y;
    float zz = s0.z + s1.z + s2.z + s3.z;
    float w = s0.w + s1.w + s2.w + s3.w;
    uint2 o;
    o.x = (uint32_t)f2b(x) | ((uint32_t)f2b(y) << 16);
    o.y = (uint32_t)f2b(zz) | ((uint32_t)f2b(w) << 16);
    kvT[i] = o;
}

// ---------- out GEMM: out[b][n][e] = Q @ kvT^T, fp32 out ----------
__global__ __launch_bounds__(256) void gemm_out(const uint16_t* __restrict__ A,
                                                const uint16_t* __restrict__ Bt,
                                                float* __restrict__ C) {
    const uint16_t* Ab = A + (size_t)blockIdx.z * 4194304;
    const uint16_t* Bb = Bt + (size_t)blockIdx.z * 1048576;

    __shared__ uint16_t lA[4096];
    __shared__ uint16_t lB[4096];

    const int t = threadIdx.x;
    const int wave = t >> 6;
    const int lane = t & 63;
    const int m0 = blockIdx.y * 128;
    const int n0 = blockIdx.x * 128;
    const int wm = (wave >> 1) * 64;
    const int wn = (wave & 1) * 64;

    const int gcol = (((t & 3) ^ ((t >> 3) & 3)) * 8);
    const uint16_t* gA0 = Ab + (size_t)(m0 + (t >> 2)) * 1024 + gcol;
    const uint16_t* gB0 = Bb + (size_t)(n0 + (t >> 2)) * 1024 + gcol;
    uint16_t* lA0 = lA + wave * 512;
    uint16_t* lA1 = lA + 2048 + wave * 512;
    uint16_t* lB0 = lB + wave * 512;
    uint16_t* lB1 = lB + 2048 + wave * 512;

    f32x4 acc[4][4] = {};

    const int arow = wm + (lane & 15);
    const int brow = wn + (lane & 15);
    const int swz = (((lane >> 4) ^ (((lane & 15) >> 1) & 3)) * 8);

    for (int k0 = 0; k0 < 1024; k0 += 32) {
        __syncthreads();
        gll16(gA0 + k0, lA0);
        gll16(gA0 + (size_t)64 * 1024 + k0, lA1);
        gll16(gB0 + k0, lB0);
        gll16(gB0 + (size_t)64 * 1024 + k0, lB1);
        __syncthreads();

        bf16x8 af[4], bfr[4];
#pragma unroll
        for (int i = 0; i < 4; i++)
            af[i] = *(const bf16x8*)&lA[(arow + i * 16) * 32 + swz];
#pragma unroll
        for (int i = 0; i < 4; i++)
            bfr[i] = *(const bf16x8*)&lB[(brow + i * 16) * 32 + swz];
#pragma unroll
        for (int i = 0; i < 4; i++)
#pragma unroll
            for (int j = 0; j < 4; j++)
                acc[i][j] = __builtin_amdgcn_mfma_f32_16x16x32_bf16(af[i], bfr[j],
                                                                    acc[i][j], 0, 0, 0);
    }

    float* Cb = C + (size_t)blockIdx.z * 4194304;
    const int crow = m0 + wm + (lane >> 4) * 4;
    const int ccol = n0 + wn + (lane & 15);
#pragma unroll
    for (int i = 0; i < 4; i++)
#pragma unroll
        for (int j = 0; j < 4; j++)
#pragma unroll
            for (int r = 0; r < 4; r++)
                Cb[(size_t)(crow + i * 16 + r) * 1024 + ccol + j * 16] = acc[i][j][r];
}

// ---------- launch ----------
extern "C" void kernel_launch(void* const* d_in, const int* in_sizes, int n_in,
                              void* d_out, int out_size, void* d_ws, size_t ws_size,
                              hipStream_t stream) {
    const float* x = (const float*)d_in[0];

    uint16_t* ws = (uint16_t*)d_ws;
    uint16_t* xb  = ws;                        // [0, 16M elts); dead after proj
    float*    kvP = (float*)d_ws;              // [0, 32M elts as u16) = 64MB fp32
    uint16_t* Wt  = ws + 33554432;             // [32M, 36M) packed weights
    uint16_t* kvT = Wt;                        // reuse after proj
    uint16_t* Q   = ws + 37748736;             // [36M, 52M)
    uint16_t* KT  = ws + 54525952;             // [52M, 68M)
    uint16_t* VT  = ws + 71303168;             // [68M, 84M)

    // 1. x -> bf16
    cvt_f32_bf16<<<16384, 256, 0, stream>>>((const float4*)x, (uint2*)xb, 4194304);

    // 2. weights -> packed transposed bf16
    Ptr4 wp;
    wp.p[0] = (const float*)d_in[1];
    wp.p[1] = (const float*)d_in[2];
    wp.p[2] = (const float*)d_in[3];
    wp.p[3] = (const float*)d_in[4];
    tr_w_packed<<<dim3(16, 16, 4), 256, 0, stream>>>(wp, Wt);

    // 3. all projections + gate + K/V transpose, one dispatch
    proj_packed<<<dim3(32, 128), 256, 0, stream>>>(xb, Wt, Q, KT, VT);

    // 4. kv partials
    gemm_kv_splitk<<<dim3(8, 8, 16), 256, 0, stream>>>(VT, KT, kvP);

    // 5. reduce partials -> kvT bf16
    reduce_kv<<<4096, 256, 0, stream>>>((const float4*)kvP, (uint2*)kvT);

    // 6. out = Q @ kvT^T, fp32
    gemm_out<<<dim3(8, 32, 4), 256, 0, stream>>>(Q, kvT, (float*)d_out);
}

// Round 4
// 426.943 us; speedup vs baseline: 1.2921x; 1.2921x over previous
//
#include <hip/hip_runtime.h>
#include <stdint.h>

// ---------- types & helpers ----------
typedef short bf16x8 __attribute__((ext_vector_type(8)));
typedef float f32x4 __attribute__((ext_vector_type(4)));

__device__ __forceinline__ uint16_t f2b(float f) {
    uint32_t u = __builtin_bit_cast(uint32_t, f);
    return (uint16_t)((u + 0x7fffu + ((u >> 16) & 1u)) >> 16);
}

__device__ __forceinline__ void gll16(const void* g, void* l) {
    __builtin_amdgcn_global_load_lds(
        (const __attribute__((address_space(1))) uint32_t*)(uintptr_t)g,
        (__attribute__((address_space(3))) uint32_t*)(uint32_t)(uintptr_t)l,
        16, 0, 0);
}

// ---------- fp32 -> bf16 convert (x) ----------
__global__ __launch_bounds__(256) void cvt_f32_bf16(const float4* __restrict__ in,
                                                    uint2* __restrict__ out, int nvec) {
    int i = blockIdx.x * 256 + threadIdx.x;
    if (i >= nvec) return;
    float4 v = in[i];
    uint2 o;
    o.x = (uint32_t)f2b(v.x) | ((uint32_t)f2b(v.y) << 16);
    o.y = (uint32_t)f2b(v.z) | ((uint32_t)f2b(v.w) << 16);
    out[i] = o;
}

// ---------- weight transpose into PACKED layout ----------
// Packed Bt [4096][1024] (k-major rows = W^T[e][d]):
// Q half, rows [0,2048): for e in [0,1024), mat in {0=QL,1=QR}:
//   row = (e>>6)*128 + ((e>>5)&1)*64 + mat*32 + ((e>>4)&1)*16 + (e&15)
//   -> wave j-subtiles 0,1 = QL, 2,3 = QR for the same 32 e's (register gate).
// KV half, rows [2048,4096): row = 2048 + (e>>6)*128 + (mat-2)*64 + (e&63)  (2=K,3=V)
struct Ptr4 { const float* p[4]; };

__global__ __launch_bounds__(256) void tr_w_packed(Ptr4 wp, uint16_t* __restrict__ out) {
    const int m = blockIdx.z;                  // 0=QL 1=QR 2=K 3=V
    const float* in = wp.p[m];
    __shared__ uint16_t tile[64][68];
    int t = threadIdx.x;
    int r0 = blockIdx.y * 64;                  // d-tile
    int c0 = blockIdx.x * 64;                  // e-tile
    for (int p = 0; p < 4; p++) {
        int row = p * 16 + (t >> 4);
        int c4 = (t & 15) * 4;
        float4 v = *(const float4*)&in[(size_t)(r0 + row) * 1024 + c0 + c4];
        tile[row][c4 + 0] = f2b(v.x);
        tile[row][c4 + 1] = f2b(v.y);
        tile[row][c4 + 2] = f2b(v.z);
        tile[row][c4 + 3] = f2b(v.w);
    }
    __syncthreads();
    for (int p = 0; p < 4; p++) {
        int a = p * 16 + (t >> 4);             // local e index
        int b4 = (t & 15) * 4;
        uint32_t x0 = tile[b4 + 0][a], x1 = tile[b4 + 1][a];
        uint32_t x2 = tile[b4 + 2][a], x3 = tile[b4 + 3][a];
        uint2 pk;
        pk.x = x0 | (x1 << 16);
        pk.y = x2 | (x3 << 16);
        int pr;
        if (m < 2)
            pr = (c0 >> 6) * 128 + ((a >> 5) & 1) * 64 + m * 32 + ((a >> 4) & 1) * 16 + (a & 15);
        else
            pr = 2048 + (c0 >> 6) * 128 + (m - 2) * 64 + a;
        *(uint2*)&out[(size_t)pr * 1024 + r0 + b4] = pk;
    }
}

// ---------- packed projection GEMM (m97 economics, plain staging) ----------
// grid (32,128). bx<16: gate blocks -> Q[m][e] bf16 (register-only gate).
// bx>=16: K/V blocks -> KT/VT [b][e][tok] bf16 via per-wave LDS transpose.
union SmemP {
    struct { uint16_t lA[4096]; uint16_t lB[4096]; } s;   // 16 KB staging
    uint16_t tr[4][64][68];                                // 34816 B transpose scratch
};

__global__ __launch_bounds__(256) void proj_packed(const uint16_t* __restrict__ A,
                                                   const uint16_t* __restrict__ B,
                                                   uint16_t* __restrict__ Q,
                                                   uint16_t* __restrict__ KT,
                                                   uint16_t* __restrict__ VT) {
    __shared__ SmemP u;
    const int t = threadIdx.x;
    const int wave = t >> 6;
    const int lane = t & 63;
    const int m0 = blockIdx.y * 128;
    const int n0 = blockIdx.x * 128;
    const int wm = (wave >> 1) * 64;
    const int wn = (wave & 1) * 64;

    const uint16_t* gA0 = A + (size_t)(m0 + (t >> 2)) * 1024 + (t & 3) * 8;
    const uint16_t* gB0 = B + (size_t)(n0 + (t >> 2)) * 1024 + (t & 3) * 8;
    uint16_t* lA0 = u.s.lA + wave * 512;
    uint16_t* lA1 = u.s.lA + 2048 + wave * 512;
    uint16_t* lB0 = u.s.lB + wave * 512;
    uint16_t* lB1 = u.s.lB + 2048 + wave * 512;

    f32x4 acc[4][4] = {};

    const int arow = wm + (lane & 15);
    const int brow = wn + (lane & 15);
    const int koff = (lane >> 4) * 8;

    for (int k0 = 0; k0 < 1024; k0 += 32) {
        __syncthreads();
        gll16(gA0 + k0, lA0);
        gll16(gA0 + (size_t)64 * 1024 + k0, lA1);
        gll16(gB0 + k0, lB0);
        gll16(gB0 + (size_t)64 * 1024 + k0, lB1);
        __syncthreads();

        bf16x8 af[4], bfr[4];
#pragma unroll
        for (int i = 0; i < 4; i++)
            af[i] = *(const bf16x8*)&u.s.lA[(arow + i * 16) * 32 + koff];
#pragma unroll
        for (int i = 0; i < 4; i++)
            bfr[i] = *(const bf16x8*)&u.s.lB[(brow + i * 16) * 32 + koff];
#pragma unroll
        for (int i = 0; i < 4; i++)
#pragma unroll
            for (int j = 0; j < 4; j++)
                acc[i][j] = __builtin_amdgcn_mfma_f32_16x16x32_bf16(af[i], bfr[j],
                                                                    acc[i][j], 0, 0, 0);
    }

    const int rl = (lane >> 4) * 4;
    const int cl = lane & 15;

    if (blockIdx.x < 16) {
        // ---- register-only gate: j=0,1 are QL, j=2,3 are QR for the same e's
        const int e0 = blockIdx.x * 64 + (wave & 1) * 32;
#pragma unroll
        for (int i = 0; i < 4; i++)
#pragma unroll
            for (int jj = 0; jj < 2; jj++)
#pragma unroll
                for (int r = 0; r < 4; r++) {
                    float g = acc[i][jj][r] * acc[i][jj + 2][r];
                    Q[(size_t)(m0 + wm + i * 16 + rl + r) * 1024 + e0 + jj * 16 + cl] = f2b(g);
                }
    } else {
        // ---- K/V transpose epilogue (wn=0 -> K, wn=1 -> V)
        __syncthreads();   // all waves done reading staging LDS before reuse
        const int batch = m0 >> 12;
        const int tok0 = (m0 & 4095) + wm;
        const int e0 = (blockIdx.x - 16) * 64;
        uint16_t* O = ((wave & 1) ? VT : KT) + (size_t)batch * 4194304;
#pragma unroll
        for (int i = 0; i < 4; i++)
#pragma unroll
            for (int j = 0; j < 4; j++) {
                int col = j * 16 + cl;
                int row0 = i * 16 + rl;
                uint2 pk;
                pk.x = (uint32_t)f2b(acc[i][j][0]) | ((uint32_t)f2b(acc[i][j][1]) << 16);
                pk.y = (uint32_t)f2b(acc[i][j][2]) | ((uint32_t)f2b(acc[i][j][3]) << 16);
                *(uint2*)&u.tr[wave][col][row0] = pk;
            }
        __builtin_amdgcn_s_waitcnt(0);   // drain LDS writes before cross-lane reads
#pragma unroll
        for (int dd = 0; dd < 16; dd++) {
            int f = dd * 4 + (lane >> 4);
            int t4 = cl * 4;
            uint2 v = *(const uint2*)&u.tr[wave][f][t4];
            *(uint2*)&O[(size_t)(e0 + f) * 4096 + tok0 + t4] = v;
        }
    }
}

// ---------- split-K(2) kv GEMM: P[z] = VT[b,:,ks*2048+2048) @ KT-slice^T ----------
__global__ __launch_bounds__(256) void gemm_kv_splitk(const uint16_t* __restrict__ VT,
                                                      const uint16_t* __restrict__ KT,
                                                      float* __restrict__ P) {
    const int z = blockIdx.z;
    const int batch = z >> 1, ks = z & 1;
    const uint16_t* Ab = VT + (size_t)batch * 4194304 + ks * 2048;
    const uint16_t* Bb = KT + (size_t)batch * 4194304 + ks * 2048;

    __shared__ uint16_t lA[4096];
    __shared__ uint16_t lB[4096];

    const int t = threadIdx.x;
    const int wave = t >> 6;
    const int lane = t & 63;
    const int m0 = blockIdx.y * 128;
    const int n0 = blockIdx.x * 128;
    const int wm = (wave >> 1) * 64;
    const int wn = (wave & 1) * 64;

    const uint16_t* gA0 = Ab + (size_t)(m0 + (t >> 2)) * 4096 + (t & 3) * 8;
    const uint16_t* gB0 = Bb + (size_t)(n0 + (t >> 2)) * 4096 + (t & 3) * 8;
    uint16_t* lA0 = lA + wave * 512;
    uint16_t* lA1 = lA + 2048 + wave * 512;
    uint16_t* lB0 = lB + wave * 512;
    uint16_t* lB1 = lB + 2048 + wave * 512;

    f32x4 acc[4][4] = {};

    const int arow = wm + (lane & 15);
    const int brow = wn + (lane & 15);
    const int koff = (lane >> 4) * 8;

    for (int k0 = 0; k0 < 2048; k0 += 32) {
        __syncthreads();
        gll16(gA0 + k0, lA0);
        gll16(gA0 + (size_t)64 * 4096 + k0, lA1);
        gll16(gB0 + k0, lB0);
        gll16(gB0 + (size_t)64 * 4096 + k0, lB1);
        __syncthreads();

        bf16x8 af[4], bfr[4];
#pragma unroll
        for (int i = 0; i < 4; i++)
            af[i] = *(const bf16x8*)&lA[(arow + i * 16) * 32 + koff];
#pragma unroll
        for (int i = 0; i < 4; i++)
            bfr[i] = *(const bf16x8*)&lB[(brow + i * 16) * 32 + koff];
#pragma unroll
        for (int i = 0; i < 4; i++)
#pragma unroll
            for (int j = 0; j < 4; j++)
                acc[i][j] = __builtin_amdgcn_mfma_f32_16x16x32_bf16(af[i], bfr[j],
                                                                    acc[i][j], 0, 0, 0);
    }

    float* Pb = P + (size_t)z * 1048576;
    const int crow = m0 + wm + (lane >> 4) * 4;
    const int ccol = n0 + wn + (lane & 15);
#pragma unroll
    for (int i = 0; i < 4; i++)
#pragma unroll
        for (int j = 0; j < 4; j++)
#pragma unroll
            for (int r = 0; r < 4; r++)
                Pb[(size_t)(crow + i * 16 + r) * 1024 + ccol + j * 16] = acc[i][j][r];
}

// ---------- reduce 2 fp32 partials -> bf16 kvT ----------
__global__ __launch_bounds__(256) void reduce_kv(const float4* __restrict__ P,
                                                 uint2* __restrict__ kvT) {
    int i = blockIdx.x * 256 + threadIdx.x;   // [0, 1048576) float4 units
    int b = i >> 18;
    int r = i & 262143;
    const float4* base = P + (size_t)b * 524288 + r;
    float4 s0 = base[0];
    float4 s1 = base[262144];
    float x = s0.x + s1.x;
    float y = s0.y + s1.y;
    float zz = s0.z + s1.z;
    float w = s0.w + s1.w;
    uint2 o;
    o.x = (uint32_t)f2b(x) | ((uint32_t)f2b(y) << 16);
    o.y = (uint32_t)f2b(zz) | ((uint32_t)f2b(w) << 16);
    kvT[i] = o;
}

// ---------- out GEMM: out[b][n][e] = Q @ kvT^T, fp32 out ----------
__global__ __launch_bounds__(256) void gemm_out(const uint16_t* __restrict__ A,
                                                const uint16_t* __restrict__ Bt,
                                                float* __restrict__ C) {
    const uint16_t* Ab = A + (size_t)blockIdx.z * 4194304;
    const uint16_t* Bb = Bt + (size_t)blockIdx.z * 1048576;

    __shared__ uint16_t lA[4096];
    __shared__ uint16_t lB[4096];

    const int t = threadIdx.x;
    const int wave = t >> 6;
    const int lane = t & 63;
    const int m0 = blockIdx.y * 128;
    const int n0 = blockIdx.x * 128;
    const int wm = (wave >> 1) * 64;
    const int wn = (wave & 1) * 64;

    const uint16_t* gA0 = Ab + (size_t)(m0 + (t >> 2)) * 1024 + (t & 3) * 8;
    const uint16_t* gB0 = Bb + (size_t)(n0 + (t >> 2)) * 1024 + (t & 3) * 8;
    uint16_t* lA0 = lA + wave * 512;
    uint16_t* lA1 = lA + 2048 + wave * 512;
    uint16_t* lB0 = lB + wave * 512;
    uint16_t* lB1 = lB + 2048 + wave * 512;

    f32x4 acc[4][4] = {};

    const int arow = wm + (lane & 15);
    const int brow = wn + (lane & 15);
    const int koff = (lane >> 4) * 8;

    for (int k0 = 0; k0 < 1024; k0 += 32) {
        __syncthreads();
        gll16(gA0 + k0, lA0);
        gll16(gA0 + (size_t)64 * 1024 + k0, lA1);
        gll16(gB0 + k0, lB0);
        gll16(gB0 + (size_t)64 * 1024 + k0, lB1);
        __syncthreads();

        bf16x8 af[4], bfr[4];
#pragma unroll
        for (int i = 0; i < 4; i++)
            af[i] = *(const bf16x8*)&lA[(arow + i * 16) * 32 + koff];
#pragma unroll
        for (int i = 0; i < 4; i++)
            bfr[i] = *(const bf16x8*)&lB[(brow + i * 16) * 32 + koff];
#pragma unroll
        for (int i = 0; i < 4; i++)
#pragma unroll
            for (int j = 0; j < 4; j++)
                acc[i][j] = __builtin_amdgcn_mfma_f32_16x16x32_bf16(af[i], bfr[j],
                                                                    acc[i][j], 0, 0, 0);
    }

    float* Cb = C + (size_t)blockIdx.z * 4194304;
    const int crow = m0 + wm + (lane >> 4) * 4;
    const int ccol = n0 + wn + (lane & 15);
#pragma unroll
    for (int i = 0; i < 4; i++)
#pragma unroll
        for (int j = 0; j < 4; j++)
#pragma unroll
            for (int r = 0; r < 4; r++)
                Cb[(size_t)(crow + i * 16 + r) * 1024 + ccol + j * 16] = acc[i][j][r];
}

// ---------- launch ----------
extern "C" void kernel_launch(void* const* d_in, const int* in_sizes, int n_in,
                              void* d_out, int out_size, void* d_ws, size_t ws_size,
                              hipStream_t stream) {
    const float* x = (const float*)d_in[0];

    uint16_t* ws = (uint16_t*)d_ws;
    uint16_t* xb  = ws;                        // [0, 32MB); dead after proj
    float*    kvP = (float*)d_ws;              // [0, 32MB) fp32 partials (after proj)
    uint16_t* Wt  = ws + 33554432;             // [64MB, 72MB) packed weights
    uint16_t* kvT = Wt;                        // reuse after proj
    uint16_t* Q   = ws + 37748736;             // [72MB, 104MB)
    uint16_t* KT  = ws + 54525952;             // [104MB, 136MB)
    uint16_t* VT  = ws + 71303168;             // [136MB, 168MB)

    // 1. x -> bf16
    cvt_f32_bf16<<<16384, 256, 0, stream>>>((const float4*)x, (uint2*)xb, 4194304);

    // 2. weights -> packed transposed bf16
    Ptr4 wp;
    wp.p[0] = (const float*)d_in[1];
    wp.p[1] = (const float*)d_in[2];
    wp.p[2] = (const float*)d_in[3];
    wp.p[3] = (const float*)d_in[4];
    tr_w_packed<<<dim3(16, 16, 4), 256, 0, stream>>>(wp, Wt);

    // 3. all projections + register gate + K/V transpose, one dispatch
    proj_packed<<<dim3(32, 128), 256, 0, stream>>>(xb, Wt, Q, KT, VT);

    // 4. kv partials (split-K = 2)
    gemm_kv_splitk<<<dim3(8, 8, 8), 256, 0, stream>>>(VT, KT, kvP);

    // 5. reduce partials -> kvT bf16
    reduce_kv<<<4096, 256, 0, stream>>>((const float4*)kvP, (uint2*)kvT);

    // 6. out = Q @ kvT^T, fp32
    gemm_out<<<dim3(8, 32, 4), 256, 0, stream>>>(Q, kvT, (float*)d_out);
}